// Round 5
// baseline (1486.701 us; speedup 1.0000x reference)
//
#include <hip/hip_runtime.h>

// Problem constants (fixed by the reference).
#define NN 204800
#define BB 4096
#define FF 256
#define CAP 72    // LDS-staged rows per graph, bf16 (36 KB)
#define CPAD 264  // ctx tile row pad (u16) to break bank conflicts

typedef unsigned short u16;
typedef unsigned int u32;
typedef short bf16x8 __attribute__((ext_vector_type(8)));   // 8 bf16 (4 VGPRs)
typedef float f32x4  __attribute__((ext_vector_type(4)));   // MFMA accumulator
typedef float f4     __attribute__((ext_vector_type(4)));   // nontemporal loads

__device__ __forceinline__ u16 rne_bf16(float f){
    union { u32 v; float f; } t; t.f = f;
    u32 lsb = (t.v >> 16) & 1u;
    t.v += 0x7fffu + lsb;
    return (u16)(t.v >> 16);
}
__device__ __forceinline__ float bf16_to_f(u16 h){
    union { u32 v; float f; } t; t.v = (u32)h << 16; return t.f;
}
__device__ __forceinline__ void cvt4(const float* __restrict__ src, u16* __restrict__ dst){
    float4 v = *(const float4*)src;
    ushort4 h;
    h.x = rne_bf16(v.x); h.y = rne_bf16(v.y);
    h.z = rne_bf16(v.z); h.w = rne_bf16(v.w);
    *(ushort4*)dst = h;
}

// Wave-level 64-ary lower_bound on sorted seg[0..NN).
__device__ __forceinline__ int lb64(const int* __restrict__ seg, int val, int lane){
    int lo = 0, hi = NN;
    while (lo < hi){
        int span = (hi - lo + 63) >> 6;
        int pos = lo + lane * span;
        int v = (pos < hi) ? seg[pos] : 0x7fffffff;
        unsigned long long m = __ballot(v < val);
        if (m == 0ull){ hi = lo; break; }
        int h = 63 - __clzll(m);
        int nlo = lo + h * span + 1;
        int nhi = lo + (h + 1) * span;
        lo = nlo;
        hi = nhi < hi ? nhi : hi;
    }
    return lo;
}

// Weight conversion: Wp + Wih + Whh = 458752 elems = 448 chunks x (256 thr x ushort4).
#define CVT_V4 ((FF*FF + 2*3*FF*FF) / 4)   // 114688
#define CVT_BLOCKS 448

// One cvt chunk (256 ushort4), done by a full block; chunk id c in [0, 448).
__device__ __forceinline__ void cvt_chunk(int c, int tid,
        const float* __restrict__ Wp, const float* __restrict__ Wih,
        const float* __restrict__ Whh, u16* __restrict__ Wp_b,
        u16* __restrict__ Wih_b, u16* __restrict__ Whh_b){
    int j = (c * 256 + tid) * 4;
    const int n_wp = FF * FF, n_w3 = 3 * FF * FF;
    if (j < n_wp)                cvt4(Wp + j, Wp_b + j);
    else if ((j -= n_wp) < n_w3) cvt4(Wih + j, Wih_b + j);
    else                         cvt4(Whh + (j - n_w3), Whh_b + (j - n_w3));
}

// ctr layout (ints): [0..447] chunk claim flags; [448] chunks-done count;
// [512+t] tile arrival counters (t in [0,256)).
//
// Fused mega-kernel. Block g: attention for graph g (4 waves), release fence,
// tile-counter arrival. The 16th finisher of tile t=g>>4 continues into proj+GRU
// for graphs 16t..16t+15 (overlaps other tiles' attention; no wait — it IS last).
// Weights: blocks 0..447 claim+convert chunk g at block START, fence, bump done.
// A GEMM continuation fast-path checks done==448; if not, it STEALS unclaimed
// chunks itself (idempotent), then waits only on chunks held by actively-running
// blocks -> deadlock-free under any dispatch order / scheduler.
__global__ __launch_bounds__(256, 4) void k_fused(
        const float* __restrict__ x, const float* __restrict__ Wl,
        const float* __restrict__ bl, const float* __restrict__ gfe,
        const int* __restrict__ seg,
        const float* __restrict__ Wp, const float* __restrict__ Wih,
        const float* __restrict__ Whh, const float* __restrict__ bp,
        const float* __restrict__ bih, const float* __restrict__ bhh,
        int* __restrict__ ctr,
        float* __restrict__ gate, u16* __restrict__ s_b, u16* __restrict__ gfe_b,
        u16* __restrict__ Wp_b, u16* __restrict__ Wih_b, u16* __restrict__ Whh_b,
        float* __restrict__ out){
    __shared__ union {
        struct { __align__(16) u16 xs[CAP][FF]; float zs[512]; float red[16]; int sbounds[2]; } a;
        struct { __align__(16) u16 ctx[16][CPAD]; } m;   // 8.25 KB
    } sh;
    __shared__ int claim_s, rank_s, wdone_s;
    int g = blockIdx.x;
    int tid = threadIdx.x, wave = tid >> 6, lane = tid & 63;

    // ---- Phase 0a: gfe row -> bf16 + c_g partial ----
    float gv = gfe[(size_t)g * FF + tid];
    gfe_b[(size_t)g * FF + tid] = rne_bf16(gv);
    float p = Wl[tid] * fmaxf(gv, 0.f);
    #pragma unroll
    for (int o = 32; o; o >>= 1) p += __shfl_xor(p, o);
    if (lane == 0) sh.a.red[8 + wave] = p;

    // ---- Phase 0b: claimed weight-cvt chunk (blocks 0..447), published EARLY ----
    if (g < CVT_BLOCKS){
        if (tid == 0) claim_s = atomicExch(&ctr[g], 1);
        __syncthreads();
        if (claim_s == 0){
            cvt_chunk(g, tid, Wp, Wih, Whh, Wp_b, Wih_b, Whh_b);
            __syncthreads();                   // all chunk stores issued+drained
            if (tid == 0){ __threadfence(); atomicAdd(&ctr[448], 1); }
        }
    }

    // ---- Phase 0c: segment bounds ----
    if (wave < 2){
        int L = lb64(seg, g + wave, lane);
        if (lane == 0) sh.a.sbounds[wave] = L;
    }
    float blv = bl[0];
    f4 wv = *(const f4*)(Wl + FF + lane * 4);
    __syncthreads();

    int s0 = sh.a.sbounds[0], cnt = sh.a.sbounds[1] - s0;
    if (tid == 0) gate[g] = cnt > 0 ? 1.f : 0.f;

    if (cnt == 0){
        s_b[(size_t)g * FF + tid] = 0;     // block-uniform path; still join protocol
    } else {
        auto st_row = [&](int row, const f4& v){
            ushort4 h;
            h.x = rne_bf16(v.x); h.y = rne_bf16(v.y);
            h.z = rne_bf16(v.z); h.w = rne_bf16(v.w);
            *(ushort4*)(&sh.a.xs[row][lane * 4]) = h;
        };
        // Phase A: 8-deep nontemporal burst, wave-strided rows
        int i = wave;
        for (; i + 28 < cnt; i += 32){
            const f4* r0 = (const f4*)(x + (size_t)(s0 + i) * FF + lane * 4);
            f4 xv[8];
            #pragma unroll
            for (int u = 0; u < 8; u++) xv[u] = __builtin_nontemporal_load(r0 + u * FF);
            float d[8];
            #pragma unroll
            for (int u = 0; u < 8; u++)
                d[u] = xv[u].x * wv.x + xv[u].y * wv.y + xv[u].z * wv.z + xv[u].w * wv.w;
            #pragma unroll
            for (int o = 32; o; o >>= 1){
                #pragma unroll
                for (int u = 0; u < 8; u++) d[u] += __shfl_xor(d[u], o);
            }
            #pragma unroll
            for (int u = 0; u < 8; u++) if (i + u * 4 < CAP) st_row(i + u * 4, xv[u]);
            if (lane == 0){
                #pragma unroll
                for (int u = 0; u < 8; u++) sh.a.zs[i + u * 4] = d[u];
            }
        }
        for (; i + 12 < cnt; i += 16){
            const f4* r0 = (const f4*)(x + (size_t)(s0 + i) * FF + lane * 4);
            f4 xv[4];
            #pragma unroll
            for (int u = 0; u < 4; u++) xv[u] = __builtin_nontemporal_load(r0 + u * FF);
            float d[4];
            #pragma unroll
            for (int u = 0; u < 4; u++)
                d[u] = xv[u].x * wv.x + xv[u].y * wv.y + xv[u].z * wv.z + xv[u].w * wv.w;
            #pragma unroll
            for (int o = 32; o; o >>= 1){
                #pragma unroll
                for (int u = 0; u < 4; u++) d[u] += __shfl_xor(d[u], o);
            }
            #pragma unroll
            for (int u = 0; u < 4; u++) if (i + u * 4 < CAP) st_row(i + u * 4, xv[u]);
            if (lane == 0){
                #pragma unroll
                for (int u = 0; u < 4; u++) sh.a.zs[i + u * 4] = d[u];
            }
        }
        for (; i < cnt; i += 4){
            f4 xv = __builtin_nontemporal_load((const f4*)(x + (size_t)(s0 + i) * FF + lane * 4));
            float d = xv.x * wv.x + xv.y * wv.y + xv.z * wv.z + xv.w * wv.w;
            #pragma unroll
            for (int o = 32; o; o >>= 1) d += __shfl_xor(d, o);
            if (i < CAP) st_row(i, xv);
            if (lane == 0) sh.a.zs[i] = d;
        }
        __syncthreads();
        // Phase B: finish c_g, leaky + max
        float cg = sh.a.red[8] + sh.a.red[9] + sh.a.red[10] + sh.a.red[11] + blv;
        float mx = -3.4e38f;
        for (int k = tid; k < cnt; k += 256){
            float t = cg + sh.a.zs[k];
            t = t >= 0.f ? t : 0.01f * t;
            sh.a.zs[k] = t;
            mx = fmaxf(mx, t);
        }
        #pragma unroll
        for (int o = 32; o; o >>= 1) mx = fmaxf(mx, __shfl_xor(mx, o));
        if (lane == 0) sh.a.red[wave] = mx;
        __syncthreads();
        mx = fmaxf(fmaxf(sh.a.red[0], sh.a.red[1]), fmaxf(sh.a.red[2], sh.a.red[3]));
        float dsum = 0.f;
        for (int k = tid; k < cnt; k += 256){
            float e = expf(sh.a.zs[k] - mx);
            sh.a.zs[k] = e;
            dsum += e;
        }
        #pragma unroll
        for (int o = 32; o; o >>= 1) dsum += __shfl_xor(dsum, o);
        if (lane == 0) sh.a.red[4 + wave] = dsum;
        __syncthreads();
        float inv = 1.f / (sh.a.red[4] + sh.a.red[5] + sh.a.red[6] + sh.a.red[7]);
        // Phase C: weighted sum; thread = feature
        float acc = 0.f;
        int lim = cnt < CAP ? cnt : CAP;
        for (int k = 0; k < lim; k++) acc += sh.a.zs[k] * bf16_to_f(sh.a.xs[k][tid]);
        for (int k = CAP; k < cnt; k++) acc += sh.a.zs[k] * x[(size_t)(s0 + k) * FF + tid];
        s_b[(size_t)g * FF + tid] = rne_bf16(acc * inv);
    }

    // ---- Finish protocol: release s_b/gfe_b/gate, tile arrival ----
    __threadfence();
    __syncthreads();
    if (tid == 0) rank_s = atomicAdd(&ctr[512 + (g >> 4)], 1);
    __syncthreads();
    if (rank_s != 15) return;              // only the tile's last finisher continues

    // ---- Weights ready? Fast path in practice; steal-and-finish otherwise ----
    if (tid == 0) wdone_s = (atomicAdd(&ctr[448], 0) >= CVT_BLOCKS) ? 1 : 0;
    __syncthreads();
    if (!wdone_s){
        for (int c = 0; c < CVT_BLOCKS; c++){
            if (tid == 0) claim_s = atomicExch(&ctr[c], 1);
            __syncthreads();
            if (claim_s == 0){
                cvt_chunk(c, tid, Wp, Wih, Whh, Wp_b, Wih_b, Whh_b);
                __syncthreads();
                if (tid == 0){ __threadfence(); atomicAdd(&ctr[448], 1); }
            }
            __syncthreads();
        }
        // Remaining chunks are held by RUNNING blocks that never wait -> bounded.
        if (tid == 0){
            while (atomicAdd(&ctr[448], 0) < CVT_BLOCKS) __builtin_amdgcn_s_sleep(8);
        }
        __syncthreads();
    }
    __threadfence();                       // acquire: fresh s_b/gfe_b/gate/weights

    // ---- proj+GRU for tile t (4 waves, two f-passes of 128) ----
    int g0 = (g >> 4) * 16;
    int mn = lane & 15, q = lane >> 4;
    const u16* arow = s_b + (size_t)(g0 + mn) * FF + q * 8;
    #pragma unroll 1
    for (int ph = 0; ph < 2; ph++){
        int fb = ph * 128 + wave * 32;
        f32x4 acc[2] = {};
        #pragma unroll
        for (int kb = 0; kb < 8; kb++){
            bf16x8 a = *(const bf16x8*)(arow + kb * 32);
            #pragma unroll
            for (int cc = 0; cc < 2; cc++){
                bf16x8 b = *(const bf16x8*)(Wp_b + (size_t)(fb + cc * 16 + mn) * FF + kb * 32 + q * 8);
                acc[cc] = __builtin_amdgcn_mfma_f32_16x16x32_bf16(a, b, acc[cc], 0, 0, 0);
            }
        }
        #pragma unroll
        for (int cc = 0; cc < 2; cc++){
            int f = fb + cc * 16 + mn;
            float bias = bp[f];
            #pragma unroll
            for (int r = 0; r < 4; r++){
                int gg = g0 + q * 4 + r;
                float v = acc[cc][r] + gate[gg] * bias;
                v = v > 0.f ? v : expm1f(v);
                sh.m.ctx[q * 4 + r][f] = rne_bf16(v);
            }
        }
    }
    __syncthreads();
    const u16* ag_row = gfe_b + (size_t)(g0 + mn) * FF + q * 8;
    #pragma unroll 1
    for (int ph = 0; ph < 2; ph++){
        int fb = ph * 128 + wave * 32;
        f32x4 ai[3][2] = {};
        f32x4 ah[3][2] = {};
        #pragma unroll
        for (int kb = 0; kb < 8; kb++){
            bf16x8 a_c = *(const bf16x8*)(&sh.m.ctx[mn][kb * 32 + q * 8]);
            bf16x8 a_g = *(const bf16x8*)(ag_row + kb * 32);
            #pragma unroll
            for (int s = 0; s < 3; s++){
                #pragma unroll
                for (int cc = 0; cc < 2; cc++){
                    size_t woff = (size_t)(s * FF + fb + cc * 16 + mn) * FF + kb * 32 + q * 8;
                    bf16x8 bi = *(const bf16x8*)(Wih_b + woff);
                    ai[s][cc] = __builtin_amdgcn_mfma_f32_16x16x32_bf16(a_c, bi, ai[s][cc], 0, 0, 0);
                    bf16x8 bh = *(const bf16x8*)(Whh_b + woff);
                    ah[s][cc] = __builtin_amdgcn_mfma_f32_16x16x32_bf16(a_g, bh, ah[s][cc], 0, 0, 0);
                }
            }
        }
        #pragma unroll
        for (int cc = 0; cc < 2; cc++){
            int f = fb + cc * 16 + mn;
            float bir = bih[f], biz = bih[FF + f], bin_ = bih[2 * FF + f];
            float bhr = bhh[f], bhz = bhh[FF + f], bhn = bhh[2 * FF + f];
            #pragma unroll
            for (int r = 0; r < 4; r++){
                int gg = g0 + q * 4 + r;
                float rg = 1.f / (1.f + expf(-(ai[0][cc][r] + bir + ah[0][cc][r] + bhr)));
                float zg = 1.f / (1.f + expf(-(ai[1][cc][r] + biz + ah[1][cc][r] + bhz)));
                float ng = tanhf(ai[2][cc][r] + bin_ + rg * (ah[2][cc][r] + bhn));
                float h = gfe[(size_t)gg * FF + f];
                out[(size_t)gg * FF + f] = (1.f - zg) * ng + zg * h;
            }
        }
    }
}

extern "C" void kernel_launch(void* const* d_in, const int* in_sizes, int n_in,
                              void* d_out, int out_size, void* d_ws, size_t ws_size,
                              hipStream_t stream){
    const float* node = (const float*)d_in[0];
    const float* gfe  = (const float*)d_in[1];
    const int*   seg  = (const int*)d_in[2];
    const float* Wl   = (const float*)d_in[3];
    const float* bl   = (const float*)d_in[4];
    const float* Wp   = (const float*)d_in[5];
    const float* bp   = (const float*)d_in[6];
    const float* Wih  = (const float*)d_in[7];
    const float* Whh  = (const float*)d_in[8];
    const float* bih  = (const float*)d_in[9];
    const float* bhh  = (const float*)d_in[10];
    float* out = (float*)d_out;

    // Workspace carve-up (~6 MB total). Counters FIRST (zeroed each launch).
    char* p = (char*)d_ws;
    auto alloc = [&](size_t bytes)->void*{
        void* r = (void*)p; p += (bytes + 255) & ~(size_t)255; return r;
    };
    int*   ctr   = (int*)  alloc(4096);   // [0..447] claims, [448] done, [512+t] tiles
    float* gate  = (float*)alloc(BB * sizeof(float));
    u16*   s_b   = (u16*)  alloc((size_t)BB * FF * sizeof(u16));
    u16*   gfe_b = (u16*)  alloc((size_t)BB * FF * sizeof(u16));
    u16*   Wp_b  = (u16*)  alloc((size_t)FF * FF * sizeof(u16));
    u16*   Wih_b = (u16*)  alloc((size_t)3 * FF * FF * sizeof(u16));
    u16*   Whh_b = (u16*)  alloc((size_t)3 * FF * FF * sizeof(u16));

    hipMemsetAsync(ctr, 0, 4096, stream);
    k_fused<<<BB, 256, 0, stream>>>(node, Wl, bl, gfe, seg, Wp, Wih, Whh, bp, bih, bhh,
                                    ctr, gate, s_b, gfe_b, Wp_b, Wih_b, Whh_b, out);
}

// Round 6
// 337.501 us; speedup vs baseline: 4.4050x; 4.4050x over previous
//
#include <hip/hip_runtime.h>

// Problem constants (fixed by the reference).
#define NN 204800
#define BB 4096
#define FF 256
#define CAP 56   // LDS-staged rows per graph, bf16 (28.7 KB) -> 5 blocks/CU (20 waves)

typedef unsigned short u16;
typedef unsigned int u32;
typedef short bf16x8 __attribute__((ext_vector_type(8)));   // 8 bf16 (4 VGPRs)
typedef float f32x4  __attribute__((ext_vector_type(4)));   // MFMA accumulator
typedef float f4     __attribute__((ext_vector_type(4)));   // for nontemporal loads

__device__ __forceinline__ u16 rne_bf16(float f){
    union { u32 v; float f; } t; t.f = f;
    u32 lsb = (t.v >> 16) & 1u;
    t.v += 0x7fffu + lsb;
    return (u16)(t.v >> 16);
}
__device__ __forceinline__ float bf16_to_f(u16 h){
    union { u32 v; float f; } t; t.v = (u32)h << 16; return t.f;
}
__device__ __forceinline__ void cvt4(const float* __restrict__ src, u16* __restrict__ dst){
    float4 v = *(const float4*)src;
    ushort4 h;
    h.x = rne_bf16(v.x); h.y = rne_bf16(v.y);
    h.z = rne_bf16(v.z); h.w = rne_bf16(v.w);
    *(ushort4*)dst = h;
}

// Wave-level 64-ary lower_bound on sorted seg[0..NN): first idx with seg[idx] >= val.
__device__ __forceinline__ int lb64(const int* __restrict__ seg, int val, int lane){
    int lo = 0, hi = NN;
    while (lo < hi){
        int span = (hi - lo + 63) >> 6;
        int pos = lo + lane * span;
        int v = (pos < hi) ? seg[pos] : 0x7fffffff;
        unsigned long long m = __ballot(v < val);
        if (m == 0ull){ hi = lo; break; }
        int h = 63 - __clzll(m);
        int nlo = lo + h * span + 1;
        int nhi = lo + (h + 1) * span;
        lo = nlo;
        hi = nhi < hi ? nhi : hi;
    }
    return lo;
}

// Weight-conversion share embedded in k_attn: Wp + Wih + Whh = 458752 elems
// = 114688 ushort4 = exactly blocks 0..447 x 256 threads x 1 cvt4.
#define CVT_V4 ((FF*FF + 2*3*FF*FF) / 4)   // 114688

// K1: fused attention — ONE pass over node_feats per graph (nontemporal stream).
// Also: per-block segment bounds (64-ary search, waves 0/1), gfe->bf16 row write,
// gate[g] write, and the weight fp32->bf16 conversion (first 448 blocks).
__global__ __launch_bounds__(256) void k_attn(
        const float* __restrict__ x, const float* __restrict__ Wl,
        const float* __restrict__ bl, const float* __restrict__ gfe,
        const int* __restrict__ seg, u16* __restrict__ s_b,
        u16* __restrict__ gfe_b, float* __restrict__ gate,
        const float* __restrict__ Wp, const float* __restrict__ Wih,
        const float* __restrict__ Whh, u16* __restrict__ Wp_b,
        u16* __restrict__ Wih_b, u16* __restrict__ Whh_b){
    __shared__ __align__(16) u16 xs[CAP][FF];    // 28.7 KB (bf16 staged rows)
    __shared__ float zs[512];                    // raw z, then exp weights
    __shared__ float red[16];                    // [0:4) max, [4:8) denom, [8:12) c partials
    __shared__ int sbounds[2];
    int g = blockIdx.x;
    int tid = threadIdx.x, wave = tid >> 6, lane = tid & 63;

    // Phase 0a: gfe row -> bf16 + c_g partial = sum_f Wl[f]*relu(gfe[g,f])
    float gv = gfe[(size_t)g * FF + tid];
    gfe_b[(size_t)g * FF + tid] = rne_bf16(gv);
    float p = Wl[tid] * fmaxf(gv, 0.f);
    #pragma unroll
    for (int o = 32; o; o >>= 1) p += __shfl_xor(p, o);
    if (lane == 0) red[8 + wave] = p;

    // Phase 0b: embedded weight conversion (first 448 blocks, 1 cvt4/thread)
    int gid = g * 256 + tid;
    if (gid < CVT_V4){
        int j = gid * 4;
        const int n_wp = FF * FF, n_w3 = 3 * FF * FF;
        if (j < n_wp)                cvt4(Wp + j, Wp_b + j);
        else if ((j -= n_wp) < n_w3) cvt4(Wih + j, Wih_b + j);
        else                         cvt4(Whh + (j - n_w3), Whh_b + (j - n_w3));
    }

    // Phase 0c: segment bounds (waves 0 and 1 search g and g+1)
    if (wave < 2){
        int L = lb64(seg, g + wave, lane);
        if (lane == 0) sbounds[wave] = L;
    }
    float blv = bl[0];
    f4 wv = *(const f4*)(Wl + FF + lane * 4);
    __syncthreads();

    int s0 = sbounds[0], cnt = sbounds[1] - s0;
    if (tid == 0) gate[g] = cnt > 0 ? 1.f : 0.f;
    if (cnt == 0){                   // block-uniform: safe early exit
        s_b[(size_t)g * FF + tid] = 0;
        return;
    }

    auto st_row = [&](int row, const f4& v){
        ushort4 h;
        h.x = rne_bf16(v.x); h.y = rne_bf16(v.y);
        h.z = rne_bf16(v.z); h.w = rne_bf16(v.w);
        *(ushort4*)(&xs[row][lane * 4]) = h;
    };

    // Phase A: 8-deep burst (8 outstanding 1KB row loads per wave), nontemporal.
    // Wave handles the stride-4 row sequence {wave, wave+4, ...}.
    int i = wave;
    for (; i + 28 < cnt; i += 32){
        const f4* r0 = (const f4*)(x + (size_t)(s0 + i) * FF + lane * 4);
        f4 xv[8];
        #pragma unroll
        for (int u = 0; u < 8; u++) xv[u] = __builtin_nontemporal_load(r0 + u * FF);
        float d[8];
        #pragma unroll
        for (int u = 0; u < 8; u++)
            d[u] = xv[u].x * wv.x + xv[u].y * wv.y + xv[u].z * wv.z + xv[u].w * wv.w;
        #pragma unroll
        for (int o = 32; o; o >>= 1){
            #pragma unroll
            for (int u = 0; u < 8; u++) d[u] += __shfl_xor(d[u], o);
        }
        #pragma unroll
        for (int u = 0; u < 8; u++) if (i + u * 4 < CAP) st_row(i + u * 4, xv[u]);
        if (lane == 0){
            #pragma unroll
            for (int u = 0; u < 8; u++) zs[i + u * 4] = d[u];
        }
    }
    for (; i + 12 < cnt; i += 16){
        const f4* r0 = (const f4*)(x + (size_t)(s0 + i) * FF + lane * 4);
        f4 xv[4];
        #pragma unroll
        for (int u = 0; u < 4; u++) xv[u] = __builtin_nontemporal_load(r0 + u * FF);
        float d[4];
        #pragma unroll
        for (int u = 0; u < 4; u++)
            d[u] = xv[u].x * wv.x + xv[u].y * wv.y + xv[u].z * wv.z + xv[u].w * wv.w;
        #pragma unroll
        for (int o = 32; o; o >>= 1){
            #pragma unroll
            for (int u = 0; u < 4; u++) d[u] += __shfl_xor(d[u], o);
        }
        #pragma unroll
        for (int u = 0; u < 4; u++) if (i + u * 4 < CAP) st_row(i + u * 4, xv[u]);
        if (lane == 0){
            #pragma unroll
            for (int u = 0; u < 4; u++) zs[i + u * 4] = d[u];
        }
    }
    for (; i < cnt; i += 4){
        f4 xv = __builtin_nontemporal_load((const f4*)(x + (size_t)(s0 + i) * FF + lane * 4));
        float d = xv.x * wv.x + xv.y * wv.y + xv.z * wv.z + xv.w * wv.w;
        #pragma unroll
        for (int o = 32; o; o >>= 1) d += __shfl_xor(d, o);
        if (i < CAP) st_row(i, xv);
        if (lane == 0) zs[i] = d;
    }
    __syncthreads();
    // Phase B: finish c_g, apply leaky during max pass
    float cg = red[8] + red[9] + red[10] + red[11] + blv;
    float mx = -3.4e38f;
    for (int k = tid; k < cnt; k += 256){
        float t = cg + zs[k];
        t = t >= 0.f ? t : 0.01f * t;
        zs[k] = t;
        mx = fmaxf(mx, t);
    }
    #pragma unroll
    for (int o = 32; o; o >>= 1) mx = fmaxf(mx, __shfl_xor(mx, o));
    if (lane == 0) red[wave] = mx;
    __syncthreads();
    mx = fmaxf(fmaxf(red[0], red[1]), fmaxf(red[2], red[3]));
    float dsum = 0.f;
    for (int k = tid; k < cnt; k += 256){
        float e = expf(zs[k] - mx);
        zs[k] = e;
        dsum += e;
    }
    #pragma unroll
    for (int o = 32; o; o >>= 1) dsum += __shfl_xor(dsum, o);
    if (lane == 0) red[4 + wave] = dsum;
    __syncthreads();
    float inv = 1.f / (red[4] + red[5] + red[6] + red[7]);
    // Phase C: weighted sum; thread = feature
    float acc = 0.f;
    int lim = cnt < CAP ? cnt : CAP;
    for (int k = 0; k < lim; k++) acc += zs[k] * bf16_to_f(xs[k][tid]);
    for (int k = CAP; k < cnt; k++) acc += zs[k] * x[(size_t)(s0 + k) * FF + tid];
    s_b[(size_t)g * FF + tid] = rne_bf16(acc * inv);
}

// K2: fused proj+GRU. Block = 16 graphs (one MFMA M-tile), 512 threads = 8 waves,
// wave w owns f-slice [w*32, w*32+32). Proj -> ctx tile in LDS (row pad +8 u16
// breaks the 16-way bank conflict a 256-stride would cause on ds_read_b128),
// then 6-GEMM GRU + cell epilogue.
#define CPAD 264
__global__ __launch_bounds__(512) void k_proj_gru(
        const u16* __restrict__ s_b, const u16* __restrict__ Wp_b,
        const float* __restrict__ bp, const float* __restrict__ gate,
        const u16* __restrict__ gfe_b, const u16* __restrict__ Wih_b,
        const u16* __restrict__ Whh_b, const float* __restrict__ bih,
        const float* __restrict__ bhh, const float* __restrict__ gfe,
        float* __restrict__ out){
    __shared__ __align__(16) u16 ctx_s[16][CPAD];   // 8.25 KB
    int tid = threadIdx.x;
    int w = tid >> 6, l = tid & 63;
    int mn = l & 15, q = l >> 4;
    int g0 = blockIdx.x * 16;
    int fb = w * 32;
    // ---- proj phase: ctx = ELU(s @ Wp^T + gate*bp) for 16 g x 32 f ----
    f32x4 acc[2] = {};
    const u16* arow = s_b + (size_t)(g0 + mn) * FF + q * 8;
    #pragma unroll
    for (int kb = 0; kb < 8; kb++){
        bf16x8 a = *(const bf16x8*)(arow + kb * 32);
        #pragma unroll
        for (int cc = 0; cc < 2; cc++){
            bf16x8 b = *(const bf16x8*)(Wp_b + (size_t)(fb + cc * 16 + mn) * FF + kb * 32 + q * 8);
            acc[cc] = __builtin_amdgcn_mfma_f32_16x16x32_bf16(a, b, acc[cc], 0, 0, 0);
        }
    }
    #pragma unroll
    for (int cc = 0; cc < 2; cc++){
        int f = fb + cc * 16 + mn;
        float bias = bp[f];
        #pragma unroll
        for (int r = 0; r < 4; r++){
            int g = g0 + q * 4 + r;
            float v = acc[cc][r] + gate[g] * bias;
            v = v > 0.f ? v : expm1f(v);
            ctx_s[q * 4 + r][f] = rne_bf16(v);
        }
    }
    __syncthreads();
    // ---- GRU phase: 6 GEMM tiles (ctx@Wih_r/z/n from LDS, gfe@Whh_r/z/n) ----
    f32x4 ai[3][2] = {};
    f32x4 ah[3][2] = {};
    const u16* ag_row = gfe_b + (size_t)(g0 + mn) * FF + q * 8;
    #pragma unroll
    for (int kb = 0; kb < 8; kb++){
        bf16x8 a_c = *(const bf16x8*)(&ctx_s[mn][kb * 32 + q * 8]);
        bf16x8 a_g = *(const bf16x8*)(ag_row + kb * 32);
        #pragma unroll
        for (int s = 0; s < 3; s++){
            #pragma unroll
            for (int cc = 0; cc < 2; cc++){
                size_t woff = (size_t)(s * FF + fb + cc * 16 + mn) * FF + kb * 32 + q * 8;
                bf16x8 bi = *(const bf16x8*)(Wih_b + woff);
                ai[s][cc] = __builtin_amdgcn_mfma_f32_16x16x32_bf16(a_c, bi, ai[s][cc], 0, 0, 0);
                bf16x8 bh = *(const bf16x8*)(Whh_b + woff);
                ah[s][cc] = __builtin_amdgcn_mfma_f32_16x16x32_bf16(a_g, bh, ah[s][cc], 0, 0, 0);
            }
        }
    }
    #pragma unroll
    for (int cc = 0; cc < 2; cc++){
        int f = fb + cc * 16 + mn;
        float bir = bih[f], biz = bih[FF + f], bin_ = bih[2 * FF + f];
        float bhr = bhh[f], bhz = bhh[FF + f], bhn = bhh[2 * FF + f];
        #pragma unroll
        for (int r = 0; r < 4; r++){
            int g = g0 + q * 4 + r;
            float rg = 1.f / (1.f + expf(-(ai[0][cc][r] + bir + ah[0][cc][r] + bhr)));
            float zg = 1.f / (1.f + expf(-(ai[1][cc][r] + biz + ah[1][cc][r] + bhz)));
            float ng = tanhf(ai[2][cc][r] + bin_ + rg * (ah[2][cc][r] + bhn));
            float h = gfe[(size_t)g * FF + f];
            out[(size_t)g * FF + f] = (1.f - zg) * ng + zg * h;
        }
    }
}

extern "C" void kernel_launch(void* const* d_in, const int* in_sizes, int n_in,
                              void* d_out, int out_size, void* d_ws, size_t ws_size,
                              hipStream_t stream){
    const float* node = (const float*)d_in[0];
    const float* gfe  = (const float*)d_in[1];
    const int*   seg  = (const int*)d_in[2];
    const float* Wl   = (const float*)d_in[3];
    const float* bl   = (const float*)d_in[4];
    const float* Wp   = (const float*)d_in[5];
    const float* bp   = (const float*)d_in[6];
    const float* Wih  = (const float*)d_in[7];
    const float* Whh  = (const float*)d_in[8];
    const float* bih  = (const float*)d_in[9];
    const float* bhh  = (const float*)d_in[10];
    float* out = (float*)d_out;

    // Workspace carve-up (~6 MB total).
    char* p = (char*)d_ws;
    auto alloc = [&](size_t bytes)->void*{
        void* r = (void*)p; p += (bytes + 255) & ~(size_t)255; return r;
    };
    float* gate  = (float*)alloc(BB * sizeof(float));
    u16*   s_b   = (u16*)  alloc((size_t)BB * FF * sizeof(u16));
    u16*   gfe_b = (u16*)  alloc((size_t)BB * FF * sizeof(u16));
    u16*   Wp_b  = (u16*)  alloc((size_t)FF * FF * sizeof(u16));
    u16*   Wih_b = (u16*)  alloc((size_t)3 * FF * FF * sizeof(u16));
    u16*   Whh_b = (u16*)  alloc((size_t)3 * FF * FF * sizeof(u16));

    k_attn<<<BB, 256, 0, stream>>>(node, Wl, bl, gfe, seg, s_b, gfe_b, gate,
                                   Wp, Wih, Whh, Wp_b, Wih_b, Whh_b);
    k_proj_gru<<<BB / 16, 512, 0, stream>>>(s_b, Wp_b, bp, gate, gfe_b, Wih_b, Whh_b,
                                            bih, bhh, gfe, out);
}